// Round 1
// baseline (1603.078 us; speedup 1.0000x reference)
//
#include <hip/hip_runtime.h>
#include <hip/hip_bf16.h>
#include <math.h>

// ---------------- problem constants ----------------
#define B_SZ   2
#define L_SZ   2048
#define DM     1024          // d_model
#define DI     2048          // d_inner
#define DS     16            // d_state
#define DC     4             // d_conv
#define M_SZ   (B_SZ * L_SZ) // 4096 rows
#define N_XZ   (2 * DI)      // 4096
// ws layout (floats):
//   xz : [0,                16777216)   M_SZ*N_XZ
//   xc : [16777216,         25165824)   M_SZ*DI   (conv+silu output; later aliased by y_gated)
//   Bm : [25165824,         25231360)   M_SZ*DS
//   Cm : [25231360,         25296896)   M_SZ*DS

// ---------------- fp32 tiled GEMM: C = A(MxK) @ B(KxN) + bias(N) ----------------
// baseline: 64x64 block tile, BK=16, 256 threads, 4x4 per thread
__global__ __launch_bounds__(256) void gemm_bias_kernel(
    const float* __restrict__ A, const float* __restrict__ B,
    const float* __restrict__ bias, float* __restrict__ C,
    int M, int N, int K) {
  __shared__ float As[16][65];   // +1 pad: transposed store
  __shared__ float Bs[16][64];
  const int tid  = threadIdx.x;
  const int trow = tid >> 4;     // 0..15
  const int tcol = tid & 15;     // 0..15
  const int row0 = blockIdx.y * 64;
  const int col0 = blockIdx.x * 64;

  float acc[4][4] = {};

  for (int k0 = 0; k0 < K; k0 += 16) {
    // A tile: 64 rows x 16 k (1024 elems / 256 thr = 4 each), store transposed
    #pragma unroll
    for (int i = 0; i < 4; ++i) {
      int idx = tid + i * 256;
      int r = idx >> 4, kk = idx & 15;
      As[kk][r] = A[(size_t)(row0 + r) * K + k0 + kk];
    }
    // B tile: 16 k x 64 n (fully coalesced)
    #pragma unroll
    for (int i = 0; i < 4; ++i) {
      int idx = tid + i * 256;
      int kk = idx >> 6, c = idx & 63;
      Bs[kk][c] = B[(size_t)(k0 + kk) * N + col0 + c];
    }
    __syncthreads();
    #pragma unroll
    for (int kk = 0; kk < 16; ++kk) {
      float a[4], b[4];
      #pragma unroll
      for (int i = 0; i < 4; ++i) a[i] = As[kk][trow * 4 + i];
      #pragma unroll
      for (int j = 0; j < 4; ++j) b[j] = Bs[kk][tcol * 4 + j];
      #pragma unroll
      for (int i = 0; i < 4; ++i)
        #pragma unroll
        for (int j = 0; j < 4; ++j)
          acc[i][j] = fmaf(a[i], b[j], acc[i][j]);
    }
    __syncthreads();
  }
  #pragma unroll
  for (int i = 0; i < 4; ++i) {
    int r = row0 + trow * 4 + i;
    #pragma unroll
    for (int j = 0; j < 4; ++j) {
      int c = col0 + tcol * 4 + j;
      C[(size_t)r * N + c] = acc[i][j] + bias[c];
    }
  }
}

// ---------------- depthwise causal conv (k=4, left pad 3) + SiLU ----------------
// out[t] = silu( sum_{k=0..3} xi[t+k-3]*W[k] + bc )   ; xi = xz[:, :, 0:DI]
__global__ __launch_bounds__(256) void conv_silu_kernel(
    const float* __restrict__ xz, const float* __restrict__ Wc,
    const float* __restrict__ bc, float* __restrict__ xc) {
  int idx = blockIdx.x * blockDim.x + threadIdx.x;   // over M_SZ*DI
  if (idx >= M_SZ * DI) return;
  int d  = idx & (DI - 1);
  int bl = idx >> 11;            // row index (b*L + l), DI = 2^11
  int l  = bl & (L_SZ - 1);
  float4 w = ((const float4*)Wc)[d];  // W_conv[d][0][0..3]
  const float* base = xz + (size_t)bl * N_XZ + d;
  float s = bc[d] + base[0] * w.w;                     // k=3 tap -> current t
  if (l >= 1) s = fmaf(base[-N_XZ],     w.z, s);
  if (l >= 2) s = fmaf(base[-2 * N_XZ], w.y, s);
  if (l >= 3) s = fmaf(base[-3 * N_XZ], w.x, s);
  float sig = 1.f / (1.f + expf(-s));
  xc[idx] = s * sig;
}

// ---------------- skinny GEMM: Bm = xc @ W_B + b_B ; Cm = xc @ W_C + b_C ----------------
// thread = (row, cc) with cc in [0,32): cc<16 -> B column s, else C column s
__global__ __launch_bounds__(256) void gemm_bc_kernel(
    const float* __restrict__ xc,
    const float* __restrict__ WB, const float* __restrict__ bB,
    const float* __restrict__ WC, const float* __restrict__ bC,
    float* __restrict__ Bm, float* __restrict__ Cm) {
  int t = blockIdx.x * blockDim.x + threadIdx.x;  // M_SZ*32
  int row = t >> 5;
  int cc  = t & 31;
  int s   = cc & 15;
  const float* W = (cc < 16) ? WB : WC;
  const float4* xr4 = (const float4*)(xc + (size_t)row * DI);
  float acc = 0.f;
  #pragma unroll 4
  for (int k4 = 0; k4 < DI / 4; ++k4) {
    float4 xv = xr4[k4];
    int k = k4 * 4;
    acc = fmaf(xv.x, W[(k    ) * DS + s], acc);
    acc = fmaf(xv.y, W[(k + 1) * DS + s], acc);
    acc = fmaf(xv.z, W[(k + 2) * DS + s], acc);
    acc = fmaf(xv.w, W[(k + 3) * DS + s], acc);
  }
  if (cc < 16) Bm[row * DS + s] = acc + bB[s];
  else         Cm[row * DS + s] = acc + bC[s];
}

// ---------------- selective scan (sequential over L), s-parallel ----------------
// block: 256 thr = 16 channels x 16 states; grid (DI/16, B)
// LDS-stages CHUNK steps of x, z, B, C. Writes y*sigmoid(z) (yg may alias xc:
// every element is staged into LDS before its slot is overwritten).
#define CHUNK 64
__global__ __launch_bounds__(256) void scan_kernel(
    const float* xc, const float* __restrict__ xz,
    const float* __restrict__ Bm, const float* __restrict__ Cm,
    const float* __restrict__ A_log, const float* __restrict__ Dv,
    float* yg) {
  const int b   = blockIdx.y;
  const int d0  = blockIdx.x * 16;
  const int tid = threadIdx.x;
  const int dd  = tid >> 4;    // local channel 0..15
  const int s   = tid & 15;    // state 0..15
  const int d   = d0 + dd;

  __shared__ float Xs[CHUNK][16];
  __shared__ float Zs[CHUNK][16];
  __shared__ float Bs[CHUNK][16];
  __shared__ float Cs[CHUNK][16];

  float Alog = A_log[d * DS + s];
  Alog = fminf(fmaxf(Alog, -10.f), 2.f);
  const float A  = -expf(Alog);
  const float Dd = Dv[d];
  float h = 0.f;

  for (int l0 = 0; l0 < L_SZ; l0 += CHUNK) {
    __syncthreads();   // protect LDS reuse from previous chunk
    #pragma unroll
    for (int i = 0; i < CHUNK * 16 / 256; ++i) {
      int idx = tid + i * 256;
      int l = idx >> 4, e = idx & 15;
      size_t row = (size_t)(b * L_SZ + l0 + l);
      Xs[l][e] = xc[row * DI + d0 + e];
      Zs[l][e] = xz[row * N_XZ + DI + d0 + e];
      Bs[l][e] = Bm[row * DS + e];
      Cs[l][e] = Cm[row * DS + e];
    }
    __syncthreads();
    for (int l = 0; l < CHUNK; ++l) {
      float x  = Xs[l][dd];
      float Bv = Bs[l][s];
      float Cv = Cs[l][s];
      h = fmaf(h, A, x * Bv);
      h = fminf(fmaxf(h, -100.f), 100.f);
      float p = h * Cv;
      p += __shfl_xor(p, 1, 16);
      p += __shfl_xor(p, 2, 16);
      p += __shfl_xor(p, 4, 16);
      p += __shfl_xor(p, 8, 16);
      float y = fmaf(Dd, x, p);
      y = fminf(fmaxf(y, -100.f), 100.f);
      float zv = Zs[l][dd];
      float g  = 1.f / (1.f + expf(-zv));
      if (s == 0)
        yg[((size_t)(b * L_SZ + l0 + l)) * DI + d] = y * g;
    }
  }
}

// ---------------- launch ----------------
extern "C" void kernel_launch(void* const* d_in, const int* in_sizes, int n_in,
                              void* d_out, int out_size, void* d_ws, size_t ws_size,
                              hipStream_t stream) {
  const float* x      = (const float*)d_in[0];
  const float* W_in   = (const float*)d_in[1];
  const float* b_in   = (const float*)d_in[2];
  const float* W_conv = (const float*)d_in[3];
  const float* b_conv = (const float*)d_in[4];
  const float* A_log  = (const float*)d_in[5];
  const float* Dv     = (const float*)d_in[6];
  const float* W_B    = (const float*)d_in[7];
  const float* b_B    = (const float*)d_in[8];
  const float* W_C    = (const float*)d_in[9];
  const float* b_C    = (const float*)d_in[10];
  const float* W_out  = (const float*)d_in[11];
  const float* b_out  = (const float*)d_in[12];
  float* out = (float*)d_out;

  float* ws = (float*)d_ws;
  float* xz = ws;                       // M_SZ*N_XZ   = 16777216
  float* xc = ws + (size_t)M_SZ * N_XZ; // M_SZ*DI     =  8388608
  float* Bm = xc + (size_t)M_SZ * DI;   // M_SZ*DS
  float* Cm = Bm + (size_t)M_SZ * DS;   // M_SZ*DS
  float* yg = xc;                       // alias: scan stages to LDS before overwrite

  // 1) xz = x @ W_in + b_in            (4096 x 1024 x 4096)
  {
    dim3 grid(N_XZ / 64, M_SZ / 64);
    gemm_bias_kernel<<<grid, 256, 0, stream>>>(x, W_in, b_in, xz, M_SZ, N_XZ, DM);
  }
  // 2) xc = silu(causal_dwconv(xi) + b_conv)
  {
    int n = M_SZ * DI;
    conv_silu_kernel<<<n / 256, 256, 0, stream>>>(xz, W_conv, b_conv, xc);
  }
  // 3) Bm, Cm projections
  {
    int n = M_SZ * 32;
    gemm_bc_kernel<<<n / 256, 256, 0, stream>>>(xc, W_B, b_B, W_C, b_C, Bm, Cm);
  }
  // 4) selective scan + gating (writes yg, aliasing xc)
  {
    dim3 grid(DI / 16, B_SZ);
    scan_kernel<<<grid, 256, 0, stream>>>(xc, xz, Bm, Cm, A_log, Dv, yg);
  }
  // 5) out = yg @ W_out + b_out        (4096 x 2048 x 1024)
  {
    dim3 grid(DM / 64, M_SZ / 64);
    gemm_bias_kernel<<<grid, 256, 0, stream>>>(yg, W_out, b_out, out, M_SZ, DM, DI);
  }
}

// Round 2
// 1134.747 us; speedup vs baseline: 1.4127x; 1.4127x over previous
//
#include <hip/hip_runtime.h>
#include <hip/hip_bf16.h>
#include <math.h>

// ---------------- problem constants ----------------
#define B_SZ   2
#define L_SZ   2048
#define DM     1024          // d_model
#define DI     2048          // d_inner
#define DS     16            // d_state
#define DC     4             // d_conv
#define M_SZ   (B_SZ * L_SZ) // 4096 rows
#define N_XZ   (2 * DI)      // 4096
// ws layout (floats):
//   xz : [0,                16777216)   M_SZ*N_XZ
//   xc : [16777216,         25165824)   M_SZ*DI   (conv+silu output; later aliased by y_gated)
//   Bm : [25165824,         25231360)   M_SZ*DS
//   Cm : [25231360,         25296896)   M_SZ*DS

// ---------------- fp32 tiled GEMM: C = A(MxK) @ B(KxN) + bias(N) ----------------
__global__ __launch_bounds__(256) void gemm_bias_kernel(
    const float* __restrict__ A, const float* __restrict__ B,
    const float* __restrict__ bias, float* __restrict__ C,
    int M, int N, int K) {
  __shared__ float As[16][65];   // +1 pad: transposed store
  __shared__ float Bs[16][64];
  const int tid  = threadIdx.x;
  const int trow = tid >> 4;     // 0..15
  const int tcol = tid & 15;     // 0..15
  const int row0 = blockIdx.y * 64;
  const int col0 = blockIdx.x * 64;

  float acc[4][4] = {};

  for (int k0 = 0; k0 < K; k0 += 16) {
    #pragma unroll
    for (int i = 0; i < 4; ++i) {
      int idx = tid + i * 256;
      int r = idx >> 4, kk = idx & 15;
      As[kk][r] = A[(size_t)(row0 + r) * K + k0 + kk];
    }
    #pragma unroll
    for (int i = 0; i < 4; ++i) {
      int idx = tid + i * 256;
      int kk = idx >> 6, c = idx & 63;
      Bs[kk][c] = B[(size_t)(k0 + kk) * N + col0 + c];
    }
    __syncthreads();
    #pragma unroll
    for (int kk = 0; kk < 16; ++kk) {
      float a[4], b[4];
      #pragma unroll
      for (int i = 0; i < 4; ++i) a[i] = As[kk][trow * 4 + i];
      #pragma unroll
      for (int j = 0; j < 4; ++j) b[j] = Bs[kk][tcol * 4 + j];
      #pragma unroll
      for (int i = 0; i < 4; ++i)
        #pragma unroll
        for (int j = 0; j < 4; ++j)
          acc[i][j] = fmaf(a[i], b[j], acc[i][j]);
    }
    __syncthreads();
  }
  #pragma unroll
  for (int i = 0; i < 4; ++i) {
    int r = row0 + trow * 4 + i;
    #pragma unroll
    for (int j = 0; j < 4; ++j) {
      int c = col0 + tcol * 4 + j;
      C[(size_t)r * N + c] = acc[i][j] + bias[c];
    }
  }
}

// ---------------- depthwise causal conv (k=4, left pad 3) + SiLU ----------------
__global__ __launch_bounds__(256) void conv_silu_kernel(
    const float* __restrict__ xz, const float* __restrict__ Wc,
    const float* __restrict__ bc, float* __restrict__ xc) {
  int idx = blockIdx.x * blockDim.x + threadIdx.x;   // over M_SZ*DI
  if (idx >= M_SZ * DI) return;
  int d  = idx & (DI - 1);
  int bl = idx >> 11;            // row index (b*L + l), DI = 2^11
  int l  = bl & (L_SZ - 1);
  float4 w = ((const float4*)Wc)[d];  // W_conv[d][0][0..3]
  const float* base = xz + (size_t)bl * N_XZ + d;
  float s = bc[d] + base[0] * w.w;                     // k=3 tap -> current t
  if (l >= 1) s = fmaf(base[-N_XZ],     w.z, s);
  if (l >= 2) s = fmaf(base[-2 * N_XZ], w.y, s);
  if (l >= 3) s = fmaf(base[-3 * N_XZ], w.x, s);
  float sig = 1.f / (1.f + expf(-s));
  xc[idx] = s * sig;
}

// ---------------- skinny GEMM: Bm = xc @ W_B + b_B ; Cm = xc @ W_C + b_C ----------------
__global__ __launch_bounds__(256) void gemm_bc_kernel(
    const float* __restrict__ xc,
    const float* __restrict__ WB, const float* __restrict__ bB,
    const float* __restrict__ WC, const float* __restrict__ bC,
    float* __restrict__ Bm, float* __restrict__ Cm) {
  int t = blockIdx.x * blockDim.x + threadIdx.x;  // M_SZ*32
  int row = t >> 5;
  int cc  = t & 31;
  int s   = cc & 15;
  const float* W = (cc < 16) ? WB : WC;
  const float4* xr4 = (const float4*)(xc + (size_t)row * DI);
  float acc = 0.f;
  #pragma unroll 4
  for (int k4 = 0; k4 < DI / 4; ++k4) {
    float4 xv = xr4[k4];
    int k = k4 * 4;
    acc = fmaf(xv.x, W[(k    ) * DS + s], acc);
    acc = fmaf(xv.y, W[(k + 1) * DS + s], acc);
    acc = fmaf(xv.z, W[(k + 2) * DS + s], acc);
    acc = fmaf(xv.w, W[(k + 3) * DS + s], acc);
  }
  if (cc < 16) Bm[row * DS + s] = acc + bB[s];
  else         Cm[row * DS + s] = acc + bC[s];
}

// ---------------- selective scan (sequential over L), s-parallel ----------------
// Restructured: cross-lane reduce & gating moved OFF the per-step critical path.
// Inner loop per step: 3 conflict-free LDS reads, mul/fma/med3-clip, one
// conflict-free ds_write of the partial h*C into Ps. After each 64-step chunk,
// a batched reduce phase sums Ps over s (rotated read index -> 4-way max),
// applies D*x, clip, sigmoid(z) gate, and stores coalesced.
// block: 256 thr = 16 channels x 16 states; grid (DI/16, B).
#define CHUNK 64
#define SROW  20   // padded stage-array stride (conflict-free b128 staging)
__global__ __launch_bounds__(256) void scan_kernel(
    const float* xc, const float* __restrict__ xz,
    const float* __restrict__ Bm, const float* __restrict__ Cm,
    const float* __restrict__ A_log, const float* __restrict__ Dv,
    float* yg) {
  const int b   = blockIdx.y;
  const int d0  = blockIdx.x * 16;
  const int tid = threadIdx.x;
  const int dd  = tid >> 4;    // local channel 0..15
  const int s   = tid & 15;    // state 0..15
  const int d   = d0 + dd;

  __shared__ float Xs[CHUNK * SROW];
  __shared__ float Zs[CHUNK * SROW];
  __shared__ float Bs[CHUNK * SROW];
  __shared__ float Cs[CHUNK * SROW];
  __shared__ float Ps[CHUNK * 256];   // 64 KB: partial products h*C

  float Alog = A_log[d * DS + s];
  Alog = fminf(fmaxf(Alog, -10.f), 2.f);
  const float A  = -expf(Alog);
  const float Dr = Dv[d0 + (tid & 15)];  // channel handled in reduce phase
  float h = 0.f;

  // staging coords: thread -> (row sl, col-group sc), one float4 per array
  const int sl = tid >> 2;   // 0..63
  const int sc = tid & 3;    // 0..3  (covers 16 floats/row)

  for (int l0 = 0; l0 < L_SZ; l0 += CHUNK) {
    __syncthreads();   // protect Xs/Zs (read in prev reduce) + Ps reuse
    {
      size_t row = (size_t)(b * L_SZ + l0 + sl);
      float4 xv = *(const float4*)(xc + row * DI + d0 + sc * 4);
      float4 zv = *(const float4*)(xz + row * N_XZ + DI + d0 + sc * 4);
      float4 bv = *(const float4*)(Bm + row * DS + sc * 4);
      float4 cv = *(const float4*)(Cm + row * DS + sc * 4);
      *(float4*)(Xs + sl * SROW + sc * 4) = xv;
      *(float4*)(Zs + sl * SROW + sc * 4) = zv;
      *(float4*)(Bs + sl * SROW + sc * 4) = bv;
      *(float4*)(Cs + sl * SROW + sc * 4) = cv;
    }
    __syncthreads();

    // ---- recurrence: minimal critical path ----
    #pragma unroll 8
    for (int l = 0; l < CHUNK; ++l) {
      float x  = Xs[l * SROW + dd];   // broadcast (free)
      float Bv = Bs[l * SROW + s];    // 16 addrs, 4-lane broadcast (free)
      float Cv = Cs[l * SROW + s];
      h = fmaf(h, A, x * Bv);
      h = fminf(fmaxf(h, -100.f), 100.f);   // v_med3
      Ps[l * 256 + tid] = h * Cv;           // 2-way bank alias (free)
    }
    __syncthreads();

    // ---- batched reduce + gate + store ----
    #pragma unroll
    for (int i = 0; i < 4; ++i) {
      int idx = tid + i * 256;           // 0..1023
      int l   = idx >> 4;                // 0..63
      int ddr = idx & 15;                // == tid & 15 for all i
      const float* p = Ps + l * 256 + ddr * 16;
      float v[16];
      #pragma unroll
      for (int j = 0; j < 16; ++j)
        v[j] = p[(j + ddr) & 15];        // rotated: 32-way -> 4-way conflict
      // pairwise tree sum (fixed association)
      float t0 = (v[0] + v[1]) + (v[2] + v[3]);
      float t1 = (v[4] + v[5]) + (v[6] + v[7]);
      float t2 = (v[8] + v[9]) + (v[10] + v[11]);
      float t3 = (v[12] + v[13]) + (v[14] + v[15]);
      float sum = (t0 + t1) + (t2 + t3);
      float xv = Xs[l * SROW + ddr];
      float y  = fmaf(Dr, xv, sum);
      y = fminf(fmaxf(y, -100.f), 100.f);
      float zv = Zs[l * SROW + ddr];
      float g  = 1.f / (1.f + expf(-zv));
      yg[((size_t)(b * L_SZ + l0 + l)) * DI + d0 + ddr] = y * g;
    }
  }
}

// ---------------- launch ----------------
extern "C" void kernel_launch(void* const* d_in, const int* in_sizes, int n_in,
                              void* d_out, int out_size, void* d_ws, size_t ws_size,
                              hipStream_t stream) {
  const float* x      = (const float*)d_in[0];
  const float* W_in   = (const float*)d_in[1];
  const float* b_in   = (const float*)d_in[2];
  const float* W_conv = (const float*)d_in[3];
  const float* b_conv = (const float*)d_in[4];
  const float* A_log  = (const float*)d_in[5];
  const float* Dv     = (const float*)d_in[6];
  const float* W_B    = (const float*)d_in[7];
  const float* b_B    = (const float*)d_in[8];
  const float* W_C    = (const float*)d_in[9];
  const float* b_C    = (const float*)d_in[10];
  const float* W_out  = (const float*)d_in[11];
  const float* b_out  = (const float*)d_in[12];
  float* out = (float*)d_out;

  float* ws = (float*)d_ws;
  float* xz = ws;                       // M_SZ*N_XZ   = 16777216
  float* xc = ws + (size_t)M_SZ * N_XZ; // M_SZ*DI     =  8388608
  float* Bm = xc + (size_t)M_SZ * DI;   // M_SZ*DS
  float* Cm = Bm + (size_t)M_SZ * DS;   // M_SZ*DS
  float* yg = xc;                       // alias: scan stages to LDS before overwrite

  // 1) xz = x @ W_in + b_in            (4096 x 1024 x 4096)
  {
    dim3 grid(N_XZ / 64, M_SZ / 64);
    gemm_bias_kernel<<<grid, 256, 0, stream>>>(x, W_in, b_in, xz, M_SZ, N_XZ, DM);
  }
  // 2) xc = silu(causal_dwconv(xi) + b_conv)
  {
    int n = M_SZ * DI;
    conv_silu_kernel<<<n / 256, 256, 0, stream>>>(xz, W_conv, b_conv, xc);
  }
  // 3) Bm, Cm projections
  {
    int n = M_SZ * 32;
    gemm_bc_kernel<<<n / 256, 256, 0, stream>>>(xc, W_B, b_B, W_C, b_C, Bm, Cm);
  }
  // 4) selective scan + gating (writes yg, aliasing xc)
  {
    dim3 grid(DI / 16, B_SZ);
    scan_kernel<<<grid, 256, 0, stream>>>(xc, xz, Bm, Cm, A_log, Dv, yg);
  }
  // 5) out = yg @ W_out + b_out        (4096 x 2048 x 1024)
  {
    dim3 grid(DM / 64, M_SZ / 64);
    gemm_bias_kernel<<<grid, 256, 0, stream>>>(yg, W_out, b_out, out, M_SZ, DM, DI);
  }
}

// Round 3
// 797.450 us; speedup vs baseline: 2.0103x; 1.4230x over previous
//
#include <hip/hip_runtime.h>
#include <hip/hip_bf16.h>
#include <math.h>

// ---------------- problem constants ----------------
#define B_SZ   2
#define L_SZ   2048
#define DM     1024          // d_model
#define DI     2048          // d_inner
#define DS     16            // d_state
#define DC     4             // d_conv
#define M_SZ   (B_SZ * L_SZ) // 4096 rows
#define N_XZ   (2 * DI)      // 4096
// ws layout (floats):
//   xz : [0,        16777216)   M_SZ*N_XZ
//   xc : [16777216, 25165824)   M_SZ*DI   (conv+silu out; later aliased by y_gated)
//   Bm : [25165824, 25231360)   M_SZ*DS
//   Cm : [25231360, 25296896)   M_SZ*DS

typedef short bf16x8 __attribute__((ext_vector_type(8)));
typedef float f32x4  __attribute__((ext_vector_type(4)));

// pack two fp32 -> two bf16 (RNE) in one dword (a=lo, b=hi)
__device__ __forceinline__ unsigned int pk_bf16(float a, float b) {
  unsigned int ua = __builtin_bit_cast(unsigned int, a);
  unsigned int ub = __builtin_bit_cast(unsigned int, b);
  ua += 0x7FFFu + ((ua >> 16) & 1u);
  ub += 0x7FFFu + ((ub >> 16) & 1u);
  return (ua >> 16) | (ub & 0xFFFF0000u);
}

// ---------------- fp32 GEMM (feeds the scan -> must stay fp32) ----------------
// 128x128 tile, BK=16, 256 threads, 8x8 per thread.
__global__ __launch_bounds__(256, 4) void gemm_bias_f32(
    const float* __restrict__ A, const float* __restrict__ B,
    const float* __restrict__ bias, float* __restrict__ C,
    int M, int N, int K) {
  __shared__ float As[16][132];   // transposed A tile, +4 pad
  __shared__ float Bs[16][128];
  const int tid = threadIdx.x;
  const int tr = tid >> 4;        // 0..15 (8-row block)
  const int tc = tid & 15;        // 0..15 (8-col block)
  const int row0 = blockIdx.y * 128, col0 = blockIdx.x * 128;

  float acc[8][8] = {};

  for (int k0 = 0; k0 < K; k0 += 16) {
    __syncthreads();              // protect LDS from previous iter's readers
    // A tile: 128 rows x 16 k; thread loads 2 float4 along k, stores transposed
    #pragma unroll
    for (int i = 0; i < 2; ++i) {
      int idx = tid + i * 256, r = idx >> 2, q = idx & 3;
      float4 v = *(const float4*)(A + (size_t)(row0 + r) * K + k0 + q * 4);
      As[q * 4 + 0][r] = v.x; As[q * 4 + 1][r] = v.y;
      As[q * 4 + 2][r] = v.z; As[q * 4 + 3][r] = v.w;
    }
    // B tile: 16 k x 128 n, coalesced float4
    #pragma unroll
    for (int i = 0; i < 2; ++i) {
      int idx = tid + i * 256, kk = idx >> 5, qc = idx & 31;
      *(float4*)&Bs[kk][qc * 4] =
          *(const float4*)(B + (size_t)(k0 + kk) * N + col0 + qc * 4);
    }
    __syncthreads();
    #pragma unroll
    for (int kk = 0; kk < 16; ++kk) {
      float a[8], b[8];
      *(float4*)&a[0] = *(const float4*)&As[kk][tr * 8];
      *(float4*)&a[4] = *(const float4*)&As[kk][tr * 8 + 4];
      *(float4*)&b[0] = *(const float4*)&Bs[kk][tc * 8];
      *(float4*)&b[4] = *(const float4*)&Bs[kk][tc * 8 + 4];
      #pragma unroll
      for (int i2 = 0; i2 < 8; ++i2)
        #pragma unroll
        for (int j2 = 0; j2 < 8; ++j2)
          acc[i2][j2] = fmaf(a[i2], b[j2], acc[i2][j2]);
    }
  }
  #pragma unroll
  for (int i2 = 0; i2 < 8; ++i2) {
    int r = row0 + tr * 8 + i2;
    #pragma unroll
    for (int j4 = 0; j4 < 2; ++j4) {
      int c = col0 + tc * 8 + j4 * 4;
      float4 o;
      o.x = acc[i2][j4 * 4 + 0] + bias[c + 0];
      o.y = acc[i2][j4 * 4 + 1] + bias[c + 1];
      o.z = acc[i2][j4 * 4 + 2] + bias[c + 2];
      o.w = acc[i2][j4 * 4 + 3] + bias[c + 3];
      *(float4*)(C + (size_t)r * N + c) = o;
    }
  }
}

// ---------------- bf16 MFMA GEMM for out = yg @ W_out + b (post-scan: safe) ----------------
// 128x128 tile, BK=32, 256 thr = 4 waves (2x2), each wave 4x4 16x16x32 frags.
// fp32 inputs converted to bf16 (RNE) in-register during LDS staging.
#define LDF 20   // uints per LDS row (32 bf16 data + 8 pad = 40 bf16)
__global__ __launch_bounds__(256, 3) void gemm_out_mfma(
    const float* __restrict__ A,    // yg  (M_SZ x DI)
    const float* __restrict__ B,    // W_out (DI x DM)
    const float* __restrict__ bias, float* __restrict__ C) {
  __shared__ unsigned int As[128 * LDF];  // [row][k] bf16 pairs
  __shared__ unsigned int Bs[128 * LDF];  // [col][k] bf16 pairs (transposed)
  const int tid  = threadIdx.x;
  const int lane = tid & 63, wave = tid >> 6;
  const int wr = wave >> 1, wc = wave & 1;
  const int lm = lane & 15, lq = lane >> 4;
  const int row0 = blockIdx.y * 128, col0 = blockIdx.x * 128;

  f32x4 acc[4][4];
  #pragma unroll
  for (int i = 0; i < 4; ++i)
    #pragma unroll
    for (int j = 0; j < 4; ++j) acc[i][j] = (f32x4){0.f, 0.f, 0.f, 0.f};

  for (int k0 = 0; k0 < DI; k0 += 32) {
    __syncthreads();
    // A: 128 rows x 32 k; float4 along k -> bf16x4 (8B) store
    #pragma unroll
    for (int i = 0; i < 4; ++i) {
      int idx = tid + i * 256, r = idx >> 3, q = idx & 7;
      float4 v = *(const float4*)(A + (size_t)(row0 + r) * DI + k0 + q * 4);
      *(uint2*)&As[r * LDF + q * 2] =
          make_uint2(pk_bf16(v.x, v.y), pk_bf16(v.z, v.w));
    }
    // B: 32 k x 128 n -> [n][k]; gather 4 k's per n (coalesced over n)
    #pragma unroll
    for (int i = 0; i < 4; ++i) {
      int idx = tid + i * 256, n = idx & 127, kq = idx >> 7;
      const float* bp = B + (size_t)(k0 + kq * 4) * DM + col0 + n;
      float b0 = bp[0], b1 = bp[DM], b2 = bp[2 * DM], b3 = bp[3 * DM];
      *(uint2*)&Bs[n * LDF + kq * 2] =
          make_uint2(pk_bf16(b0, b1), pk_bf16(b2, b3));
    }
    __syncthreads();
    bf16x8 af[4], bf[4];
    #pragma unroll
    for (int i = 0; i < 4; ++i)
      af[i] = *(const bf16x8*)&As[(wr * 64 + i * 16 + lm) * LDF + lq * 4];
    #pragma unroll
    for (int j = 0; j < 4; ++j)
      bf[j] = *(const bf16x8*)&Bs[(wc * 64 + j * 16 + lm) * LDF + lq * 4];
    #pragma unroll
    for (int i = 0; i < 4; ++i)
      #pragma unroll
      for (int j = 0; j < 4; ++j)
        acc[i][j] = __builtin_amdgcn_mfma_f32_16x16x32_bf16(af[i], bf[j], acc[i][j], 0, 0, 0);
  }
  // epilogue: C/D layout col=lane&15, row=(lane>>4)*4+reg
  #pragma unroll
  for (int i = 0; i < 4; ++i) {
    int r = row0 + wr * 64 + i * 16 + lq * 4;
    #pragma unroll
    for (int j = 0; j < 4; ++j) {
      int c = col0 + wc * 64 + j * 16 + lm;
      float bs = bias[c];
      #pragma unroll
      for (int k = 0; k < 4; ++k)
        C[(size_t)(r + k) * DM + c] = acc[i][j][k] + bs;
    }
  }
}

// ---------------- depthwise causal conv (k=4, left pad 3) + SiLU ----------------
__global__ __launch_bounds__(256) void conv_silu_kernel(
    const float* __restrict__ xz, const float* __restrict__ Wc,
    const float* __restrict__ bc, float* __restrict__ xc) {
  int idx = blockIdx.x * blockDim.x + threadIdx.x;   // over M_SZ*DI
  if (idx >= M_SZ * DI) return;
  int d  = idx & (DI - 1);
  int bl = idx >> 11;            // row index (b*L + l), DI = 2^11
  int l  = bl & (L_SZ - 1);
  float4 w = ((const float4*)Wc)[d];  // W_conv[d][0][0..3]
  const float* base = xz + (size_t)bl * N_XZ + d;
  float s = bc[d] + base[0] * w.w;                     // k=3 tap -> current t
  if (l >= 1) s = fmaf(base[-N_XZ],     w.z, s);
  if (l >= 2) s = fmaf(base[-2 * N_XZ], w.y, s);
  if (l >= 3) s = fmaf(base[-3 * N_XZ], w.x, s);
  float sig = 1.f / (1.f + expf(-s));
  xc[idx] = s * sig;
}

// ---------------- skinny GEMM: Bm = xc @ W_B + b_B ; Cm = xc @ W_C + b_C ----------------
__global__ __launch_bounds__(256) void gemm_bc_kernel(
    const float* __restrict__ xc,
    const float* __restrict__ WB, const float* __restrict__ bB,
    const float* __restrict__ WC, const float* __restrict__ bC,
    float* __restrict__ Bm, float* __restrict__ Cm) {
  int t = blockIdx.x * blockDim.x + threadIdx.x;  // M_SZ*32
  int row = t >> 5;
  int cc  = t & 31;
  int s   = cc & 15;
  const float* W = (cc < 16) ? WB : WC;
  const float4* xr4 = (const float4*)(xc + (size_t)row * DI);
  float acc = 0.f;
  #pragma unroll 4
  for (int k4 = 0; k4 < DI / 4; ++k4) {
    float4 xv = xr4[k4];
    int k = k4 * 4;
    acc = fmaf(xv.x, W[(k    ) * DS + s], acc);
    acc = fmaf(xv.y, W[(k + 1) * DS + s], acc);
    acc = fmaf(xv.z, W[(k + 2) * DS + s], acc);
    acc = fmaf(xv.w, W[(k + 3) * DS + s], acc);
  }
  if (cc < 16) Bm[row * DS + s] = acc + bB[s];
  else         Cm[row * DS + s] = acc + bC[s];
}

// ---------------- selective scan (sequential over L), s-parallel ----------------
#define CHUNK 64
#define SROW  20   // padded stage-array stride
__global__ __launch_bounds__(256) void scan_kernel(
    const float* xc, const float* __restrict__ xz,
    const float* __restrict__ Bm, const float* __restrict__ Cm,
    const float* __restrict__ A_log, const float* __restrict__ Dv,
    float* yg) {
  const int b   = blockIdx.y;
  const int d0  = blockIdx.x * 16;
  const int tid = threadIdx.x;
  const int dd  = tid >> 4;    // local channel 0..15
  const int s   = tid & 15;    // state 0..15
  const int d   = d0 + dd;

  __shared__ float Xs[CHUNK * SROW];
  __shared__ float Zs[CHUNK * SROW];
  __shared__ float Bs[CHUNK * SROW];
  __shared__ float Cs[CHUNK * SROW];
  __shared__ float Ps[CHUNK * 256];   // 64 KB: partial products h*C

  float Alog = A_log[d * DS + s];
  Alog = fminf(fmaxf(Alog, -10.f), 2.f);
  const float A  = -expf(Alog);
  const float Dr = Dv[d0 + (tid & 15)];  // channel handled in reduce phase
  float h = 0.f;

  const int sl = tid >> 2;   // 0..63
  const int sc = tid & 3;    // 0..3

  for (int l0 = 0; l0 < L_SZ; l0 += CHUNK) {
    __syncthreads();
    {
      size_t row = (size_t)(b * L_SZ + l0 + sl);
      float4 xv = *(const float4*)(xc + row * DI + d0 + sc * 4);
      float4 zv = *(const float4*)(xz + row * N_XZ + DI + d0 + sc * 4);
      float4 bv = *(const float4*)(Bm + row * DS + sc * 4);
      float4 cv = *(const float4*)(Cm + row * DS + sc * 4);
      *(float4*)(Xs + sl * SROW + sc * 4) = xv;
      *(float4*)(Zs + sl * SROW + sc * 4) = zv;
      *(float4*)(Bs + sl * SROW + sc * 4) = bv;
      *(float4*)(Cs + sl * SROW + sc * 4) = cv;
    }
    __syncthreads();

    #pragma unroll 8
    for (int l = 0; l < CHUNK; ++l) {
      float x  = Xs[l * SROW + dd];
      float Bv = Bs[l * SROW + s];
      float Cv = Cs[l * SROW + s];
      h = fmaf(h, A, x * Bv);
      h = fminf(fmaxf(h, -100.f), 100.f);
      Ps[l * 256 + tid] = h * Cv;
    }
    __syncthreads();

    #pragma unroll
    for (int i = 0; i < 4; ++i) {
      int idx = tid + i * 256;
      int l   = idx >> 4;
      int ddr = idx & 15;
      const float* p = Ps + l * 256 + ddr * 16;
      float v[16];
      #pragma unroll
      for (int j = 0; j < 16; ++j)
        v[j] = p[(j + ddr) & 15];
      float t0 = (v[0] + v[1]) + (v[2] + v[3]);
      float t1 = (v[4] + v[5]) + (v[6] + v[7]);
      float t2 = (v[8] + v[9]) + (v[10] + v[11]);
      float t3 = (v[12] + v[13]) + (v[14] + v[15]);
      float sum = (t0 + t1) + (t2 + t3);
      float xv = Xs[l * SROW + ddr];
      float y  = fmaf(Dr, xv, sum);
      y = fminf(fmaxf(y, -100.f), 100.f);
      float zv = Zs[l * SROW + ddr];
      float g  = 1.f / (1.f + expf(-zv));
      yg[((size_t)(b * L_SZ + l0 + l)) * DI + d0 + ddr] = y * g;
    }
  }
}

// ---------------- launch ----------------
extern "C" void kernel_launch(void* const* d_in, const int* in_sizes, int n_in,
                              void* d_out, int out_size, void* d_ws, size_t ws_size,
                              hipStream_t stream) {
  const float* x      = (const float*)d_in[0];
  const float* W_in   = (const float*)d_in[1];
  const float* b_in   = (const float*)d_in[2];
  const float* W_conv = (const float*)d_in[3];
  const float* b_conv = (const float*)d_in[4];
  const float* A_log  = (const float*)d_in[5];
  const float* Dv     = (const float*)d_in[6];
  const float* W_B    = (const float*)d_in[7];
  const float* b_B    = (const float*)d_in[8];
  const float* W_C    = (const float*)d_in[9];
  const float* b_C    = (const float*)d_in[10];
  const float* W_out  = (const float*)d_in[11];
  const float* b_out  = (const float*)d_in[12];
  float* out = (float*)d_out;

  float* ws = (float*)d_ws;
  float* xz = ws;                       // M_SZ*N_XZ
  float* xc = ws + (size_t)M_SZ * N_XZ; // M_SZ*DI
  float* Bm = xc + (size_t)M_SZ * DI;   // M_SZ*DS
  float* Cm = Bm + (size_t)M_SZ * DS;   // M_SZ*DS
  float* yg = xc;                       // alias: scan stages to LDS before overwrite

  // 1) xz = x @ W_in + b_in            (4096 x 4096 x 1024), fp32
  {
    dim3 grid(N_XZ / 128, M_SZ / 128);
    gemm_bias_f32<<<grid, 256, 0, stream>>>(x, W_in, b_in, xz, M_SZ, N_XZ, DM);
  }
  // 2) xc = silu(causal_dwconv(xi) + b_conv)
  {
    int n = M_SZ * DI;
    conv_silu_kernel<<<n / 256, 256, 0, stream>>>(xz, W_conv, b_conv, xc);
  }
  // 3) Bm, Cm projections (fp32 -> feed the scan)
  {
    int n = M_SZ * 32;
    gemm_bc_kernel<<<n / 256, 256, 0, stream>>>(xc, W_B, b_B, W_C, b_C, Bm, Cm);
  }
  // 4) selective scan + gating (writes yg, aliasing xc)
  {
    dim3 grid(DI / 16, B_SZ);
    scan_kernel<<<grid, 256, 0, stream>>>(xc, xz, Bm, Cm, A_log, Dv, yg);
  }
  // 5) out = yg @ W_out + b_out        (4096 x 1024 x 2048), bf16 MFMA
  {
    dim3 grid(DM / 128, M_SZ / 128);
    gemm_out_mfma<<<grid, 256, 0, stream>>>(yg, W_out, b_out, out);
  }
}